// Round 14
// baseline (248.941 us; speedup 1.0000x reference)
//
#include <hip/hip_runtime.h>
#include <hip/hip_bf16.h>

// MultiHeadSelfAttention: B=8 N=1024 E=768 H=12 D=64
// Pipeline (4 launches):
//   prep  : cvt(x->bf16) + transpose-cvt(Wqkv) + transpose-cvt(Wfc), fused
//   GEMM1 : R6-proven 2-phase dbuf 128^2; epilogue -> qh/kh [b,h,n,d]
//           (Q pre-scaled by 1/sqrt(768)*log2e); V-tiles LDS-transposed
//           DIRECT to vt [b,h,d,n] (R13-proven)
//   attn  : flash attention, NO K/V staging (L2-resident per bh: 256KB),
//           ZERO barriers in loop -- waves fully independent (m169 regime);
//           exp2 softmax + defer-max + pk2 (R11-proven)
//   GEMM2 : same GEMM template, f32 out + bias
// GEMM: 128x128 tile, BK=32, 256 thr / 4 waves, dbuf 32KB LDS, one
// __syncthreads per K-iter; LDS swizzle chunk^((row>>1)&3) (0 conflicts, R5).
// ws usage: ~80 MB.

typedef unsigned short u16;
typedef unsigned int u32;
typedef __attribute__((ext_vector_type(8))) short short8;  // 8 x bf16 (4 VGPR)
typedef __attribute__((ext_vector_type(4))) float f32x4;

#define DEV static __device__ __forceinline__

DEV u16 f2bf(float f) {  // round-to-nearest-even f32 -> bf16 bits
  union { float f; u32 u; } v; v.f = f;
  return (u16)((v.u + 0x7FFFu + ((v.u >> 16) & 1u)) >> 16);
}

DEV u32 pk2(float lo, float hi) {  // pack 2 f32 -> 2 bf16 (RNE)
  union { __hip_bfloat162 h2; u32 u; } v;
  v.h2.x = __float2bfloat16(lo);
  v.h2.y = __float2bfloat16(hi);
  return v.u;
}

DEV void gload_lds16(const void* g, void* l) {
  // LDS dest is wave-uniform base; HW writes lane i at base + i*16B.
  __builtin_amdgcn_global_load_lds(
      (const __attribute__((address_space(1))) void*)g,
      (__attribute__((address_space(3))) void*)l, 16, 0, 0);
}

// ---------------- prep: cvt(x) + trcvt(Wqkv) + trcvt(Wfc), one launch ----------------
__global__ void prep_kernel(const float* __restrict__ x, u16* __restrict__ xb,
                            const float* __restrict__ Wq, u16* __restrict__ WqT,
                            const float* __restrict__ Wf, u16* __restrict__ WfT) {
  __shared__ u16 tile[64][72];
  const int b = blockIdx.x;
  const int t = threadIdx.x;
  if (b < 576) {
    const float* in;
    u16* out;
    int Nn, bid;
    if (b < 432) { in = Wq; out = WqT; Nn = 2304; bid = b; }
    else         { in = Wf; out = WfT; Nn = 768;  bid = b - 432; }
    const int K = 768;
    int ntiles = Nn >> 6;
    int tk = bid / ntiles, tn = bid % ntiles;
    int k0 = tk << 6, n0 = tn << 6;
    int r = t >> 4;            // 0..15
    int c4 = (t & 15) << 2;    // 0,4,..,60
#pragma unroll
    for (int ps = 0; ps < 4; ++ps) {
      int k = r + ps * 16;
      float4 v = *reinterpret_cast<const float4*>(&in[(size_t)(k0 + k) * Nn + n0 + c4]);
      tile[c4 + 0][k] = f2bf(v.x);
      tile[c4 + 1][k] = f2bf(v.y);
      tile[c4 + 2][k] = f2bf(v.z);
      tile[c4 + 3][k] = f2bf(v.w);
    }
    __syncthreads();
    int nr = t >> 3;           // 0..31
    int c8 = (t & 7) << 3;     // 0..56
#pragma unroll
    for (int ps = 0; ps < 2; ++ps) {
      int n = nr + ps * 32;
      uint4 v = *reinterpret_cast<const uint4*>(&tile[n][c8]);
      *reinterpret_cast<uint4*>(&out[(size_t)(n0 + n) * K + k0 + c8]) = v;
    }
  } else {
    const int n8 = (8192 * 768) / 8;
    int idx = (b - 576) * 256 + t;
    const int stride = 2048 * 256;
    for (int i = idx; i < n8; i += stride) {
      float4 a = reinterpret_cast<const float4*>(x)[2 * i];
      float4 c = reinterpret_cast<const float4*>(x)[2 * i + 1];
      uint4 o;
      o.x = f2bf(a.x) | ((u32)f2bf(a.y) << 16);
      o.y = f2bf(a.z) | ((u32)f2bf(a.w) << 16);
      o.z = f2bf(c.x) | ((u32)f2bf(c.y) << 16);
      o.w = f2bf(c.z) | ((u32)f2bf(c.w) << 16);
      reinterpret_cast<uint4*>(xb)[i] = o;
    }
  }
}

// ---------------- dbuf bf16 GEMM (R6 proven), K fixed = 768 ----------------
// MODE 0: f32 flat out.
// MODE 2: Q/K-blocks -> qh/kh [b,h,n,d] (Q scaled by 1/sqrt(768)*log2e);
//         V-blocks (n0>=1536) -> LDS-transposed -> vt [b,h,d,n] coalesced.
template <int MODE>
__global__ __launch_bounds__(256, 4) void gemm_bt(
    const u16* __restrict__ A, const u16* __restrict__ Bt,
    const float* __restrict__ bias, void* __restrict__ Cout,
    u16* __restrict__ qh, u16* __restrict__ kh, u16* __restrict__ vt,
    int Nn) {
  __shared__ u16 SMEM[17408];
  u16* const As0 = SMEM;
  u16* const As1 = SMEM + 4096;
  u16* const Bs0 = SMEM + 8192;
  u16* const Bs1 = SMEM + 12288;
  const int nTn = Nn >> 7;
  const int nwg = gridDim.x;
  int wg = blockIdx.x;
  wg = (wg & 7) * (nwg >> 3) + (wg >> 3);   // XCD swizzle (nwg % 8 == 0)
  const int tm = wg / nTn, tn = wg % nTn;
  const int m0 = tm << 7, n0 = tn << 7;
  const int tid = threadIdx.x;
  const int w = tid >> 6, lane = tid & 63;
  const int g = lane >> 4, p = lane & 15;
  const int wr = w >> 1, wc = w & 1;        // wave -> 64x64 out at (wr*64, wc*64)

  const int srow = lane >> 2;               // 0..15
  const int schunk = (lane & 3) ^ ((srow >> 1) & 3);
  const u16* Asrc = A + (size_t)(m0 + srow) * 768 + schunk * 8;
  const u16* Bsrc = Bt + (size_t)(n0 + srow) * 768 + schunk * 8;
  const int csw = (g ^ ((p >> 1) & 3)) << 3;  // u16 offset within row

  f32x4 acc[4][4] = {};

#define STAGE(kt, ap, bp)                                                       \
  do {                                                                          \
    _Pragma("unroll")                                                           \
    for (int i = 0; i < 2; ++i) {                                               \
      int trow = w * 32 + i * 16;                                               \
      gload_lds16(Asrc + (size_t)trow * 768 + (kt) * 32, (ap) + trow * 32);     \
      gload_lds16(Bsrc + (size_t)trow * 768 + (kt) * 32, (bp) + trow * 32);     \
    }                                                                           \
  } while (0)

  STAGE(0, As0, Bs0);
  __syncthreads();

  int buf = 0;
  for (int k = 0; k < 24; ++k) {
    const u16* as = buf ? As1 : As0;
    const u16* bs = buf ? Bs1 : Bs0;
    short8 af[4], bf[4];
#pragma unroll
    for (int mb = 0; mb < 4; ++mb)
      af[mb] = *reinterpret_cast<const short8*>(&as[(wr * 64 + mb * 16 + p) * 32 + csw]);
#pragma unroll
    for (int nb = 0; nb < 4; ++nb)
      bf[nb] = *reinterpret_cast<const short8*>(&bs[(wc * 64 + nb * 16 + p) * 32 + csw]);
    if (k < 23) STAGE(k + 1, buf ? As0 : As1, buf ? Bs0 : Bs1);
#pragma unroll
    for (int mb = 0; mb < 4; ++mb)
#pragma unroll
      for (int nb = 0; nb < 4; ++nb)
        acc[mb][nb] = __builtin_amdgcn_mfma_f32_16x16x32_bf16(af[mb], bf[nb], acc[mb][nb], 0, 0, 0);
    __syncthreads();
    buf ^= 1;
  }
#undef STAGE

  const float qscale = 0.05205878290161879f;  // 1/sqrt(768) * log2(e)
  if (MODE == 0) {
#pragma unroll
    for (int nb = 0; nb < 4; ++nb) {
      int ncol = n0 + wc * 64 + nb * 16 + p;
      float bv = bias[ncol];
#pragma unroll
      for (int mb = 0; mb < 4; ++mb)
#pragma unroll
        for (int r = 0; r < 4; ++r) {
          int m = m0 + wr * 64 + mb * 16 + g * 4 + r;  // C/D: row=(lane>>4)*4+reg
          ((float*)Cout)[(size_t)m * Nn + ncol] = acc[mb][nb][r] + bv;
        }
    }
  } else if (n0 < 1536) {
    // ---- Q/K blocks: [b,h,n,d] contiguous stores (R6-proven) ----
#pragma unroll
    for (int nb = 0; nb < 4; ++nb) {
      int ncol = n0 + wc * 64 + nb * 16 + p;
      float bv = bias[ncol];
      int h64 = ncol >> 6;                 // 0..23
      int which = h64 / 12;                // 0=q 1=k
      int hh = h64 - which * 12;
      int d = ncol & 63;
      u16* dst = which == 0 ? qh : kh;
      float sc = which == 0 ? qscale : 1.f;
#pragma unroll
      for (int mb = 0; mb < 4; ++mb)
#pragma unroll
        for (int r = 0; r < 4; ++r) {
          int m = m0 + wr * 64 + mb * 16 + g * 4 + r;
          int bb = m >> 10, nr = m & 1023;
          dst[(((size_t)bb * 12 + hh) * 1024 + nr) * 64 + d] = f2bf((acc[mb][nb][r] + bv) * sc);
        }
    }
  } else {
    // ---- V blocks: transpose 128x128 tile through LDS -> vt[bh][d][n] ----
#pragma unroll
    for (int nb = 0; nb < 4; ++nb) {
      int nl = wc * 64 + nb * 16 + p;
      float bv = bias[n0 + nl];
#pragma unroll
      for (int mb = 0; mb < 4; ++mb) {
        int mlb = wr * 64 + mb * 16 + g * 4;
        uint2 pkv;
        pkv.x = (u32)f2bf(acc[mb][nb][0] + bv) | ((u32)f2bf(acc[mb][nb][1] + bv) << 16);
        pkv.y = (u32)f2bf(acc[mb][nb][2] + bv) | ((u32)f2bf(acc[mb][nb][3] + bv) << 16);
        *reinterpret_cast<uint2*>(&SMEM[nl * 136 + mlb]) = pkv;
      }
    }
    __syncthreads();
    const int hhb = (n0 - 1536) >> 6;
    const int bb = m0 >> 10;
    const int nseq0 = m0 & 1023;
    const int c16 = (tid & 7) * 16;
#pragma unroll
    for (int ps = 0; ps < 4; ++ps) {
      int nl = (tid >> 3) + ps * 32;
      int hh = hhb + (nl >> 6);
      int d = nl & 63;
      u16* dst = vt + (((size_t)(bb * 12 + hh) * 64 + d) << 10) + nseq0 + c16;
      uint4 v0 = *reinterpret_cast<const uint4*>(&SMEM[nl * 136 + c16]);
      uint4 v1 = *reinterpret_cast<const uint4*>(&SMEM[nl * 136 + c16 + 8]);
      *reinterpret_cast<uint4*>(dst) = v0;
      *reinterpret_cast<uint4*>(dst + 8) = v1;
    }
  }
}

// ---------------- flash attention, NO K/V staging, ZERO loop barriers ----------------
// grid: bh(96) * 8 q-tiles of 128 rows; 512 thr / 8 waves, wave owns 16 q-rows.
// K/V per (b,h) = 256KB -> L2-resident (m169 regime: staging is pure overhead).
// Direct fragment-shaped global reads: K-tile = 64 consecutive 128B rows of
// kh; V-frag rows contiguous 16B/lane from vt. Waves fully independent --
// latency hidden by TLP (16 waves/CU at 2 blocks/CU), not by barrier-synced
// double-buffering. P-strip stays in per-wave LDS (intra-wave dep, compiler-
// ordered lgkmcnt, same as R11-R13). exp2 softmax + defer-max + pk2.
__global__ __launch_bounds__(512, 4) void attn_kernel(
    const u16* __restrict__ qh, const u16* __restrict__ kh,
    const u16* __restrict__ vt, u16* __restrict__ ao) {
  __shared__ u16 Ps[8][16 * 64];
  const int bid = blockIdx.x;
  const int qt = bid & 7;
  const int bh = bid >> 3;
  const int b = bh / 12, h = bh % 12;
  const int tid = threadIdx.x;
  const int w = tid >> 6, lane = tid & 63;
  const int g = lane >> 4, p = lane & 15;
  const int qrow = qt * 128 + w * 16;

  const u16* qbase = qh + ((size_t)bh * 1024 + qrow + p) * 64;
  short8 qf0 = *reinterpret_cast<const short8*>(qbase + g * 8);
  short8 qf1 = *reinterpret_cast<const short8*>(qbase + 32 + g * 8);

  const u16* kbase = kh + ((size_t)bh * 1024 + p) * 64;   // row p of K-tile
  const u16* vbase = vt + ((size_t)bh * 64 + p) * 1024;   // V^T row p
  u16* myp = Ps[w];

  const int sw = p & 7;
  const int c0 = (g ^ sw) << 3;              // P-strip swizzled offsets
  const int c1 = ((4 + g) ^ sw) << 3;

  float m_run = -1e30f, l_run = 0.f;
  f32x4 oacc[4] = {};

  for (int kt = 0; kt < 1024; kt += 64) {
    // ---- St = K Q^T (log2 domain), K direct from global (L2) ----
    f32x4 s[4];
#pragma unroll
    for (int jb = 0; jb < 4; ++jb) {
      const u16* kr = kbase + (size_t)(kt + jb * 16) * 64;
      short8 k0 = *reinterpret_cast<const short8*>(kr + g * 8);
      short8 k1 = *reinterpret_cast<const short8*>(kr + 32 + g * 8);
      f32x4 z = {};
      z = __builtin_amdgcn_mfma_f32_16x16x32_bf16(k0, qf0, z, 0, 0, 0);
      z = __builtin_amdgcn_mfma_f32_16x16x32_bf16(k1, qf1, z, 0, 0, 0);
      s[jb] = z;
    }

    // ---- tile max (row q = p; replicated over g after shfl) ----
    float tmax = -1e30f;
#pragma unroll
    for (int jb = 0; jb < 4; ++jb)
#pragma unroll
      for (int r = 0; r < 4; ++r) tmax = fmaxf(tmax, s[jb][r]);
    tmax = fmaxf(tmax, __shfl_xor(tmax, 16));
    tmax = fmaxf(tmax, __shfl_xor(tmax, 32));

    // ---- defer-max: rescale only when growth > 8 (log2 units) ----
    if (!__all(tmax - m_run <= 8.f)) {
      float m_new = fmaxf(m_run, tmax);
      float alpha = __builtin_amdgcn_exp2f(m_run - m_new);
      float al[4];
#pragma unroll
      for (int r = 0; r < 4; ++r) al[r] = __shfl(alpha, g * 4 + r);
#pragma unroll
      for (int nb = 0; nb < 4; ++nb)
#pragma unroll
        for (int r = 0; r < 4; ++r) oacc[nb][r] *= al[r];
      l_run *= alpha;
      m_run = m_new;
    }

    // ---- P = exp2(S - m); row-sum ----
    float lsum = 0.f;
#pragma unroll
    for (int jb = 0; jb < 4; ++jb)
#pragma unroll
      for (int r = 0; r < 4; ++r) {
        float e = __builtin_amdgcn_exp2f(s[jb][r] - m_run);
        s[jb][r] = e;
        lsum += e;
      }
    lsum += __shfl_xor(lsum, 16);
    lsum += __shfl_xor(lsum, 32);
    l_run += lsum;

    // ---- P -> per-wave LDS strip (bf16), XOR-swizzled ----
#pragma unroll
    for (int jb = 0; jb < 4; ++jb) {
      uint2 pkv;
      pkv.x = pk2(s[jb][0], s[jb][1]);
      pkv.y = pk2(s[jb][2], s[jb][3]);
      int c = 2 * jb + (g >> 1);
      *reinterpret_cast<uint2*>(&myp[p * 64 + ((c ^ sw) << 3) + ((g & 1) << 2)]) = pkv;
    }

    // ---- O += P V, V direct from global (L2) ----
    short8 pa0 = *reinterpret_cast<const short8*>(&myp[p * 64 + c0]);
    short8 pa1 = *reinterpret_cast<const short8*>(&myp[p * 64 + c1]);
#pragma unroll
    for (int nb = 0; nb < 4; ++nb) {
      const u16* vr = vbase + (size_t)(nb * 16) * 1024 + kt;
      short8 v0 = *reinterpret_cast<const short8*>(vr + g * 8);
      short8 v1 = *reinterpret_cast<const short8*>(vr + 32 + g * 8);
      oacc[nb] = __builtin_amdgcn_mfma_f32_16x16x32_bf16(pa0, v0, oacc[nb], 0, 0, 0);
      oacc[nb] = __builtin_amdgcn_mfma_f32_16x16x32_bf16(pa1, v1, oacc[nb], 0, 0, 0);
    }
  }

  // ---- finalize: divide by row sum, store bf16 to ao[b, q, h*64+d] ----
  float li[4];
#pragma unroll
  for (int r = 0; r < 4; ++r) li[r] = 1.f / __shfl(l_run, g * 4 + r);
  u16* obase = ao + ((size_t)(b * 1024 + qrow)) * 768 + h * 64;
#pragma unroll
  for (int nb = 0; nb < 4; ++nb)
#pragma unroll
    for (int r = 0; r < 4; ++r)
      obase[(size_t)(g * 4 + r) * 768 + nb * 16 + p] = f2bf(oacc[nb][r] * li[r]);
}

// ---------------- launch ----------------
extern "C" void kernel_launch(void* const* d_in, const int* in_sizes, int n_in,
                              void* d_out, int out_size, void* d_ws, size_t ws_size,
                              hipStream_t stream) {
  const float* x = (const float*)d_in[0];      // [8,1024,768]
  const float* Wqkv = (const float*)d_in[1];   // [768,2304]
  const float* bqkv = (const float*)d_in[2];   // [2304]
  const float* Wfc = (const float*)d_in[3];    // [768,768]
  const float* bfc = (const float*)d_in[4];    // [768]
  float* out = (float*)d_out;                  // [8,1024,768] f32

  char* ws = (char*)d_ws;
  u16* xb    = (u16*)(ws);                 // 12,582,912 B : x bf16 [8192][768]
  u16* wqkvT = (u16*)(ws + 12582912);      //  3,538,944 B : [2304][768]
  u16* wfcT  = (u16*)(ws + 16121856);      //  1,179,648 B : [768][768]
  u16* qh    = (u16*)(ws + 17301504);      // 12,582,912 B : [96][1024][64] (scaled)
  u16* kh    = (u16*)(ws + 29884416);      // 12,582,912 B : [96][1024][64]
  u16* vt    = (u16*)(ws + 55050240);      // 12,582,912 B : [96][64][1024]
  u16* ao    = (u16*)(ws + 67633152);      // 12,582,912 B : [8192][768]

  prep_kernel<<<2624, 256, 0, stream>>>(x, xb, Wqkv, wqkvT, Wfc, wfcT);
  gemm_bt<2><<<64 * 18, 256, 0, stream>>>(xb, wqkvT, bqkv, nullptr, qh, kh, vt, 2304);
  attn_kernel<<<96 * 8, 512, 0, stream>>>(qh, kh, vt, ao);
  gemm_bt<0><<<64 * 6, 256, 0, stream>>>(ao, wfcT, bfc, out, nullptr, nullptr, nullptr, 768);
}

// Round 15
// 124.169 us; speedup vs baseline: 2.0049x; 2.0049x over previous
//
#include <hip/hip_runtime.h>
#include <hip/hip_bf16.h>

// MultiHeadSelfAttention: B=8 N=1024 E=768 H=12 D=64
// Pipeline (4 launches) -- R13 configuration (124.0us best):
//   prep  : cvt(x->bf16) + transpose-cvt(Wqkv) + transpose-cvt(Wfc), fused
//   GEMM1 : R6-proven 2-phase dbuf 128^2; epilogue -> qh/kh [b,h,n,d]
//           (Q pre-scaled by 1/sqrt(768)*log2e); V-tiles LDS-transposed
//           DIRECT to vt [b,h,d,n] (R13-proven)
//   attn  : flash attention, K/V LDS dbuf + XOR swizzle (staging IS the
//           prefetch -- R14's direct-global version hit 181us, latency-bound);
//           exp2 softmax + defer-max + pk2 (R11-proven)
//   GEMM2 : same GEMM template, f32 out + bias
// GEMM: 128x128 tile, BK=32, 256 thr / 4 waves, dbuf 32KB LDS, one
// __syncthreads per K-iter; LDS swizzle chunk^((row>>1)&3) (0 conflicts, R5).
// ws usage: ~80 MB.

typedef unsigned short u16;
typedef unsigned int u32;
typedef __attribute__((ext_vector_type(8))) short short8;  // 8 x bf16 (4 VGPR)
typedef __attribute__((ext_vector_type(4))) float f32x4;

#define DEV static __device__ __forceinline__

DEV u16 f2bf(float f) {  // round-to-nearest-even f32 -> bf16 bits
  union { float f; u32 u; } v; v.f = f;
  return (u16)((v.u + 0x7FFFu + ((v.u >> 16) & 1u)) >> 16);
}

DEV u32 pk2(float lo, float hi) {  // pack 2 f32 -> 2 bf16 (RNE)
  union { __hip_bfloat162 h2; u32 u; } v;
  v.h2.x = __float2bfloat16(lo);
  v.h2.y = __float2bfloat16(hi);
  return v.u;
}

DEV void gload_lds16(const void* g, void* l) {
  // LDS dest is wave-uniform base; HW writes lane i at base + i*16B.
  __builtin_amdgcn_global_load_lds(
      (const __attribute__((address_space(1))) void*)g,
      (__attribute__((address_space(3))) void*)l, 16, 0, 0);
}

// ---------------- prep: cvt(x) + trcvt(Wqkv) + trcvt(Wfc), one launch ----------------
__global__ void prep_kernel(const float* __restrict__ x, u16* __restrict__ xb,
                            const float* __restrict__ Wq, u16* __restrict__ WqT,
                            const float* __restrict__ Wf, u16* __restrict__ WfT) {
  __shared__ u16 tile[64][72];
  const int b = blockIdx.x;
  const int t = threadIdx.x;
  if (b < 576) {
    const float* in;
    u16* out;
    int Nn, bid;
    if (b < 432) { in = Wq; out = WqT; Nn = 2304; bid = b; }
    else         { in = Wf; out = WfT; Nn = 768;  bid = b - 432; }
    const int K = 768;
    int ntiles = Nn >> 6;
    int tk = bid / ntiles, tn = bid % ntiles;
    int k0 = tk << 6, n0 = tn << 6;
    int r = t >> 4;            // 0..15
    int c4 = (t & 15) << 2;    // 0,4,..,60
#pragma unroll
    for (int ps = 0; ps < 4; ++ps) {
      int k = r + ps * 16;
      float4 v = *reinterpret_cast<const float4*>(&in[(size_t)(k0 + k) * Nn + n0 + c4]);
      tile[c4 + 0][k] = f2bf(v.x);
      tile[c4 + 1][k] = f2bf(v.y);
      tile[c4 + 2][k] = f2bf(v.z);
      tile[c4 + 3][k] = f2bf(v.w);
    }
    __syncthreads();
    int nr = t >> 3;           // 0..31
    int c8 = (t & 7) << 3;     // 0..56
#pragma unroll
    for (int ps = 0; ps < 2; ++ps) {
      int n = nr + ps * 32;
      uint4 v = *reinterpret_cast<const uint4*>(&tile[n][c8]);
      *reinterpret_cast<uint4*>(&out[(size_t)(n0 + n) * K + k0 + c8]) = v;
    }
  } else {
    const int n8 = (8192 * 768) / 8;
    int idx = (b - 576) * 256 + t;
    const int stride = 2048 * 256;
    for (int i = idx; i < n8; i += stride) {
      float4 a = reinterpret_cast<const float4*>(x)[2 * i];
      float4 c = reinterpret_cast<const float4*>(x)[2 * i + 1];
      uint4 o;
      o.x = f2bf(a.x) | ((u32)f2bf(a.y) << 16);
      o.y = f2bf(a.z) | ((u32)f2bf(a.w) << 16);
      o.z = f2bf(c.x) | ((u32)f2bf(c.y) << 16);
      o.w = f2bf(c.z) | ((u32)f2bf(c.w) << 16);
      reinterpret_cast<uint4*>(xb)[i] = o;
    }
  }
}

// ---------------- dbuf bf16 GEMM (R6 proven), K fixed = 768 ----------------
// MODE 0: f32 flat out.
// MODE 2: Q/K-blocks -> qh/kh [b,h,n,d] (Q scaled by 1/sqrt(768)*log2e);
//         V-blocks (n0>=1536) -> LDS-transposed -> vt [b,h,d,n] coalesced.
template <int MODE>
__global__ __launch_bounds__(256, 4) void gemm_bt(
    const u16* __restrict__ A, const u16* __restrict__ Bt,
    const float* __restrict__ bias, void* __restrict__ Cout,
    u16* __restrict__ qh, u16* __restrict__ kh, u16* __restrict__ vt,
    int Nn) {
  __shared__ u16 SMEM[17408];
  u16* const As0 = SMEM;
  u16* const As1 = SMEM + 4096;
  u16* const Bs0 = SMEM + 8192;
  u16* const Bs1 = SMEM + 12288;
  const int nTn = Nn >> 7;
  const int nwg = gridDim.x;
  int wg = blockIdx.x;
  wg = (wg & 7) * (nwg >> 3) + (wg >> 3);   // XCD swizzle (nwg % 8 == 0)
  const int tm = wg / nTn, tn = wg % nTn;
  const int m0 = tm << 7, n0 = tn << 7;
  const int tid = threadIdx.x;
  const int w = tid >> 6, lane = tid & 63;
  const int g = lane >> 4, p = lane & 15;
  const int wr = w >> 1, wc = w & 1;        // wave -> 64x64 out at (wr*64, wc*64)

  const int srow = lane >> 2;               // 0..15
  const int schunk = (lane & 3) ^ ((srow >> 1) & 3);
  const u16* Asrc = A + (size_t)(m0 + srow) * 768 + schunk * 8;
  const u16* Bsrc = Bt + (size_t)(n0 + srow) * 768 + schunk * 8;
  const int csw = (g ^ ((p >> 1) & 3)) << 3;  // u16 offset within row

  f32x4 acc[4][4] = {};

#define STAGE(kt, ap, bp)                                                       \
  do {                                                                          \
    _Pragma("unroll")                                                           \
    for (int i = 0; i < 2; ++i) {                                               \
      int trow = w * 32 + i * 16;                                               \
      gload_lds16(Asrc + (size_t)trow * 768 + (kt) * 32, (ap) + trow * 32);     \
      gload_lds16(Bsrc + (size_t)trow * 768 + (kt) * 32, (bp) + trow * 32);     \
    }                                                                           \
  } while (0)

  STAGE(0, As0, Bs0);
  __syncthreads();

  int buf = 0;
  for (int k = 0; k < 24; ++k) {
    const u16* as = buf ? As1 : As0;
    const u16* bs = buf ? Bs1 : Bs0;
    short8 af[4], bf[4];
#pragma unroll
    for (int mb = 0; mb < 4; ++mb)
      af[mb] = *reinterpret_cast<const short8*>(&as[(wr * 64 + mb * 16 + p) * 32 + csw]);
#pragma unroll
    for (int nb = 0; nb < 4; ++nb)
      bf[nb] = *reinterpret_cast<const short8*>(&bs[(wc * 64 + nb * 16 + p) * 32 + csw]);
    if (k < 23) STAGE(k + 1, buf ? As0 : As1, buf ? Bs0 : Bs1);
#pragma unroll
    for (int mb = 0; mb < 4; ++mb)
#pragma unroll
      for (int nb = 0; nb < 4; ++nb)
        acc[mb][nb] = __builtin_amdgcn_mfma_f32_16x16x32_bf16(af[mb], bf[nb], acc[mb][nb], 0, 0, 0);
    __syncthreads();
    buf ^= 1;
  }
#undef STAGE

  const float qscale = 0.05205878290161879f;  // 1/sqrt(768) * log2(e)
  if (MODE == 0) {
#pragma unroll
    for (int nb = 0; nb < 4; ++nb) {
      int ncol = n0 + wc * 64 + nb * 16 + p;
      float bv = bias[ncol];
#pragma unroll
      for (int mb = 0; mb < 4; ++mb)
#pragma unroll
        for (int r = 0; r < 4; ++r) {
          int m = m0 + wr * 64 + mb * 16 + g * 4 + r;  // C/D: row=(lane>>4)*4+reg
          ((float*)Cout)[(size_t)m * Nn + ncol] = acc[mb][nb][r] + bv;
        }
    }
  } else if (n0 < 1536) {
    // ---- Q/K blocks: [b,h,n,d] contiguous stores (R6-proven) ----
#pragma unroll
    for (int nb = 0; nb < 4; ++nb) {
      int ncol = n0 + wc * 64 + nb * 16 + p;
      float bv = bias[ncol];
      int h64 = ncol >> 6;                 // 0..23
      int which = h64 / 12;                // 0=q 1=k
      int hh = h64 - which * 12;
      int d = ncol & 63;
      u16* dst = which == 0 ? qh : kh;
      float sc = which == 0 ? qscale : 1.f;
#pragma unroll
      for (int mb = 0; mb < 4; ++mb)
#pragma unroll
        for (int r = 0; r < 4; ++r) {
          int m = m0 + wr * 64 + mb * 16 + g * 4 + r;
          int bb = m >> 10, nr = m & 1023;
          dst[(((size_t)bb * 12 + hh) * 1024 + nr) * 64 + d] = f2bf((acc[mb][nb][r] + bv) * sc);
        }
    }
  } else {
    // ---- V blocks: transpose 128x128 tile through LDS -> vt[bh][d][n] ----
#pragma unroll
    for (int nb = 0; nb < 4; ++nb) {
      int nl = wc * 64 + nb * 16 + p;
      float bv = bias[n0 + nl];
#pragma unroll
      for (int mb = 0; mb < 4; ++mb) {
        int mlb = wr * 64 + mb * 16 + g * 4;
        uint2 pkv;
        pkv.x = (u32)f2bf(acc[mb][nb][0] + bv) | ((u32)f2bf(acc[mb][nb][1] + bv) << 16);
        pkv.y = (u32)f2bf(acc[mb][nb][2] + bv) | ((u32)f2bf(acc[mb][nb][3] + bv) << 16);
        *reinterpret_cast<uint2*>(&SMEM[nl * 136 + mlb]) = pkv;
      }
    }
    __syncthreads();
    const int hhb = (n0 - 1536) >> 6;
    const int bb = m0 >> 10;
    const int nseq0 = m0 & 1023;
    const int c16 = (tid & 7) * 16;
#pragma unroll
    for (int ps = 0; ps < 4; ++ps) {
      int nl = (tid >> 3) + ps * 32;
      int hh = hhb + (nl >> 6);
      int d = nl & 63;
      u16* dst = vt + (((size_t)(bb * 12 + hh) * 64 + d) << 10) + nseq0 + c16;
      uint4 v0 = *reinterpret_cast<const uint4*>(&SMEM[nl * 136 + c16]);
      uint4 v1 = *reinterpret_cast<const uint4*>(&SMEM[nl * 136 + c16 + 8]);
      *reinterpret_cast<uint4*>(dst) = v0;
      *reinterpret_cast<uint4*>(dst + 8) = v1;
    }
  }
}

// ---------------- flash attention (R13-proven staged version) ----------------
// grid: bh(96) * 8 q-tiles of 128 rows; 512 thr / 8 waves, wave owns 16 q-rows.
// K/V tiles double-buffered in LDS via global_load_lds (the staging IS the
// prefetch: issue tile t+1 before computing tile t; R14's direct-global
// variant was 6.5x slower, latency-bound). XOR-swizzled LDS; exp2 softmax;
// defer-max (T13, THR=8 log2 units); pk2 P-pack.
__global__ __launch_bounds__(512, 6) void attn_kernel(
    const u16* __restrict__ qh, const u16* __restrict__ kh,
    const u16* __restrict__ vt, u16* __restrict__ ao) {
  __shared__ u16 Ks[2][64 * 64];
  __shared__ u16 Vs[2][64 * 64];
  __shared__ u16 Ps[8][16 * 64];
  const int bid = blockIdx.x;
  const int qt = bid & 7;
  const int bh = bid >> 3;
  const int b = bh / 12, h = bh % 12;
  const int tid = threadIdx.x;
  const int w = tid >> 6, lane = tid & 63;
  const int g = lane >> 4, p = lane & 15;
  const int qrow = qt * 128 + w * 16;

  const u16* qbase = qh + ((size_t)bh * 1024 + qrow + p) * 64;
  short8 qf0 = *reinterpret_cast<const short8*>(qbase + g * 8);
  short8 qf1 = *reinterpret_cast<const short8*>(qbase + 32 + g * 8);

  const int ci = w * 64 + lane;              // 0..511
  const int crow = ci >> 3;                  // 0..63
  const int csw = (ci & 7) ^ (crow & 7);     // swizzled source chunk
  const u16* ksrc = kh + (((size_t)bh * 1024 + crow) << 6) + csw * 8;
  const u16* vsrc = vt + ((size_t)bh * 64 + crow) * 1024 + csw * 8;
  u16* myp = Ps[w];

  const int sw = p & 7;
  const int c0 = (g ^ sw) << 3;
  const int c1 = ((4 + g) ^ sw) << 3;

  float m_run = -1e30f, l_run = 0.f;
  f32x4 oacc[4] = {};

  gload_lds16(ksrc, &Ks[0][w * 512]);
  gload_lds16(vsrc, &Vs[0][w * 512]);
  __syncthreads();

  int buf = 0;
  for (int kt = 0; kt < 1024; kt += 64) {
    if (kt < 960) {
      gload_lds16(ksrc + ((kt + 64) << 6), &Ks[buf ^ 1][w * 512]);
      gload_lds16(vsrc + (kt + 64), &Vs[buf ^ 1][w * 512]);
    }

    // ---- St = K Q^T (log2 domain) ----
    f32x4 s[4];
    __builtin_amdgcn_s_setprio(1);
#pragma unroll
    for (int jb = 0; jb < 4; ++jb) {
      const u16* kb = &Ks[buf][(jb * 16 + p) * 64];
      short8 k0 = *reinterpret_cast<const short8*>(kb + c0);
      short8 k1 = *reinterpret_cast<const short8*>(kb + c1);
      f32x4 z = {};
      z = __builtin_amdgcn_mfma_f32_16x16x32_bf16(k0, qf0, z, 0, 0, 0);
      z = __builtin_amdgcn_mfma_f32_16x16x32_bf16(k1, qf1, z, 0, 0, 0);
      s[jb] = z;
    }
    __builtin_amdgcn_s_setprio(0);

    // ---- tile max (row q = p; replicated over g after shfl) ----
    float tmax = -1e30f;
#pragma unroll
    for (int jb = 0; jb < 4; ++jb)
#pragma unroll
      for (int r = 0; r < 4; ++r) tmax = fmaxf(tmax, s[jb][r]);
    tmax = fmaxf(tmax, __shfl_xor(tmax, 16));
    tmax = fmaxf(tmax, __shfl_xor(tmax, 32));

    // ---- defer-max: rescale only when growth > 8 (log2 units) ----
    if (!__all(tmax - m_run <= 8.f)) {
      float m_new = fmaxf(m_run, tmax);
      float alpha = __builtin_amdgcn_exp2f(m_run - m_new);
      float al[4];
#pragma unroll
      for (int r = 0; r < 4; ++r) al[r] = __shfl(alpha, g * 4 + r);
#pragma unroll
      for (int nb = 0; nb < 4; ++nb)
#pragma unroll
        for (int r = 0; r < 4; ++r) oacc[nb][r] *= al[r];
      l_run *= alpha;
      m_run = m_new;
    }

    // ---- P = exp2(S - m); row-sum ----
    float lsum = 0.f;
#pragma unroll
    for (int jb = 0; jb < 4; ++jb)
#pragma unroll
      for (int r = 0; r < 4; ++r) {
        float e = __builtin_amdgcn_exp2f(s[jb][r] - m_run);
        s[jb][r] = e;
        lsum += e;
      }
    lsum += __shfl_xor(lsum, 16);
    lsum += __shfl_xor(lsum, 32);
    l_run += lsum;

    // ---- P -> per-wave LDS strip (bf16), XOR-swizzled ----
#pragma unroll
    for (int jb = 0; jb < 4; ++jb) {
      uint2 pkv;
      pkv.x = pk2(s[jb][0], s[jb][1]);
      pkv.y = pk2(s[jb][2], s[jb][3]);
      int c = 2 * jb + (g >> 1);
      *reinterpret_cast<uint2*>(&myp[p * 64 + ((c ^ sw) << 3) + ((g & 1) << 2)]) = pkv;
    }

    // ---- O += P V ----
    short8 pa0 = *reinterpret_cast<const short8*>(&myp[p * 64 + c0]);
    short8 pa1 = *reinterpret_cast<const short8*>(&myp[p * 64 + c1]);
    __builtin_amdgcn_s_setprio(1);
#pragma unroll
    for (int nb = 0; nb < 4; ++nb) {
      const u16* vb = &Vs[buf][(nb * 16 + p) * 64];
      short8 v0 = *reinterpret_cast<const short8*>(vb + c0);
      short8 v1 = *reinterpret_cast<const short8*>(vb + c1);
      oacc[nb] = __builtin_amdgcn_mfma_f32_16x16x32_bf16(pa0, v0, oacc[nb], 0, 0, 0);
      oacc[nb] = __builtin_amdgcn_mfma_f32_16x16x32_bf16(pa1, v1, oacc[nb], 0, 0, 0);
    }
    __builtin_amdgcn_s_setprio(0);

    __syncthreads();
    buf ^= 1;
  }

  // ---- finalize: divide by row sum, store bf16 to ao[b, q, h*64+d] ----
  float li[4];
#pragma unroll
  for (int r = 0; r < 4; ++r) li[r] = 1.f / __shfl(l_run, g * 4 + r);
  u16* obase = ao + ((size_t)(b * 1024 + qrow)) * 768 + h * 64;
#pragma unroll
  for (int nb = 0; nb < 4; ++nb)
#pragma unroll
    for (int r = 0; r < 4; ++r)
      obase[(size_t)(g * 4 + r) * 768 + nb * 16 + p] = f2bf(oacc[nb][r] * li[r]);
}

// ---------------- launch ----------------
extern "C" void kernel_launch(void* const* d_in, const int* in_sizes, int n_in,
                              void* d_out, int out_size, void* d_ws, size_t ws_size,
                              hipStream_t stream) {
  const float* x = (const float*)d_in[0];      // [8,1024,768]
  const float* Wqkv = (const float*)d_in[1];   // [768,2304]
  const float* bqkv = (const float*)d_in[2];   // [2304]
  const float* Wfc = (const float*)d_in[3];    // [768,768]
  const float* bfc = (const float*)d_in[4];    // [768]
  float* out = (float*)d_out;                  // [8,1024,768] f32

  char* ws = (char*)d_ws;
  u16* xb    = (u16*)(ws);                 // 12,582,912 B : x bf16 [8192][768]
  u16* wqkvT = (u16*)(ws + 12582912);      //  3,538,944 B : [2304][768]
  u16* wfcT  = (u16*)(ws + 16121856);      //  1,179,648 B : [768][768]
  u16* qh    = (u16*)(ws + 17301504);      // 12,582,912 B : [96][1024][64] (scaled)
  u16* kh    = (u16*)(ws + 29884416);      // 12,582,912 B : [96][1024][64]
  u16* vt    = (u16*)(ws + 55050240);      // 12,582,912 B : [96][64][1024]
  u16* ao    = (u16*)(ws + 67633152);      // 12,582,912 B : [8192][768]

  prep_kernel<<<2624, 256, 0, stream>>>(x, xb, Wqkv, wqkvT, Wfc, wfcT);
  gemm_bt<2><<<64 * 18, 256, 0, stream>>>(xb, wqkvT, bqkv, nullptr, qh, kh, vt, 2304);
  attn_kernel<<<96 * 8, 512, 0, stream>>>(qh, kh, vt, ao);
  gemm_bt<0><<<64 * 6, 256, 0, stream>>>(ao, wfcT, bfc, out, nullptr, nullptr, nullptr, 768);
}